// Round 6
// baseline (184.407 us; speedup 1.0000x reference)
//
#include <hip/hip_runtime.h>
#include <hip/hip_bf16.h>

#define DIM_  768
#define NH    12
#define HD    64
#define BB    2
#define NN    2048
#define MM    (BB*NN)      // 4096
#define QKVD  (3*DIM_)     // 2304

typedef __attribute__((ext_vector_type(8))) short          bf16x8;
typedef __attribute__((ext_vector_type(4))) float          f32x4;

__device__ __forceinline__ unsigned short f2bf(float f) {
    __hip_bfloat16 h = __float2bfloat16(f);
    unsigned short u; __builtin_memcpy(&u, &h, 2); return u;
}

__device__ __forceinline__ unsigned int cvt_pk_bf16(float lo, float hi) {
    unsigned int r;
    asm("v_cvt_pk_bf16_f32 %0, %1, %2" : "=v"(r) : "v"(lo), "v"(hi));
    return r;
}

// async global->LDS, 16B/lane. LDS dest = wave-uniform base + lane*16 (HW rule).
__device__ __forceinline__ void gload16(const void* g, void* lds) {
    __builtin_amdgcn_global_load_lds(
        (const __attribute__((address_space(1))) void*)g,
        (__attribute__((address_space(3))) void*)lds, 16, 0, 0);
}

// one fused cast kernel: x, w_qkv, w_fc -> bf16
__global__ __launch_bounds__(256)
void cast_all(const float* __restrict__ x, const float* __restrict__ wqkv,
              const float* __restrict__ wfc, unsigned short* __restrict__ xb,
              unsigned short* __restrict__ wqkvb, unsigned short* __restrict__ wfcb)
{
    const int NV0 = (MM * DIM_) / 4;
    const int NV1 = NV0 + (QKVD * DIM_) / 4;
    const int NV2 = NV1 + (DIM_ * DIM_) / 4;
    int i = blockIdx.x * 256 + threadIdx.x;
    if (i >= NV2) return;
    const float* src; unsigned short* dst;
    if (i < NV0)      { src = x + (size_t)i * 4;            dst = xb + (size_t)i * 4; }
    else if (i < NV1) { size_t j = i - NV0; src = wqkv + j * 4; dst = wqkvb + j * 4; }
    else              { size_t j = i - NV1; src = wfc + j * 4;  dst = wfcb + j * 4; }
    float4 v = *(const float4*)src;
    ushort4 o; o.x = f2bf(v.x); o.y = f2bf(v.y); o.z = f2bf(v.z); o.w = f2bf(v.w);
    *(ushort4*)dst = o;
}

// ---------------- GEMM1: qkv = x @ w_qkv^T -> per-head q (pre-scaled), k, v^T ---
// 128x128 tile, 4 waves, BK=32, 2-phase dbuf; LDS-transposed coalesced epilogue.
__global__ __launch_bounds__(256)
void gemm_qkv(const unsigned short* __restrict__ A, const unsigned short* __restrict__ W,
              unsigned short* __restrict__ qh, unsigned short* __restrict__ kh,
              unsigned short* __restrict__ vth)
{
    __shared__ unsigned short smem[4][4096];   // As = smem[0..1], Bs = smem[2..3]; pool = all 16384
    unsigned short* const pool = &smem[0][0];
    const int tid = threadIdx.x, lane = tid & 63, wave = tid >> 6;
    const int wr = wave >> 1, wc = wave & 1;
    const int n0 = blockIdx.x * 128, m0 = blockIdx.y * 128;
    const int ldrow = lane >> 2, ldg = lane & 3;
    const int g = lane >> 4, q15 = lane & 15;
    constexpr float QSCALE = 0.18033688011112042f;   // 64^-0.5 * log2(e)

    f32x4 acc[4][4];
    #pragma unroll
    for (int i = 0; i < 4; ++i)
        #pragma unroll
        for (int j = 0; j < 4; ++j) acc[i][j] = (f32x4){0.f, 0.f, 0.f, 0.f};

    #define STAGE_G(buf, k0)                                                         \
        _Pragma("unroll")                                                            \
        for (int rd = 0; rd < 2; ++rd) {                                             \
            const int chunk = rd * 4 + wave;                                         \
            const int row = chunk * 16 + ldrow;                                      \
            gload16(A + (size_t)(m0 + row) * DIM_ + (k0) + ldg * 8,                  \
                    (char*)&smem[buf][0] + chunk * 1024);                            \
            gload16(W + (size_t)(n0 + row) * DIM_ + (k0) + ldg * 8,                  \
                    (char*)&smem[2 + (buf)][0] + chunk * 1024);                      \
        }

    STAGE_G(0, 0);
    __syncthreads();
    int cur = 0;
    for (int kt = 0; kt < DIM_ / 32; ++kt) {
        if (kt < DIM_ / 32 - 1) { STAGE_G(cur ^ 1, (kt + 1) * 32); }
        bf16x8 af[4], bw[4];
        #pragma unroll
        for (int i = 0; i < 4; ++i)
            af[i] = *(const bf16x8*)((const char*)&smem[cur][0] + (wr*64 + i*16 + q15) * 64 + g * 16);
        #pragma unroll
        for (int j = 0; j < 4; ++j)
            bw[j] = *(const bf16x8*)((const char*)&smem[2 + cur][0] + (wc*64 + j*16 + q15) * 64 + g * 16);
        #pragma unroll
        for (int i = 0; i < 4; ++i)
            #pragma unroll
            for (int j = 0; j < 4; ++j)
                acc[i][j] = __builtin_amdgcn_mfma_f32_16x16x32_bf16(af[i], bw[j], acc[i][j], 0, 0, 0);
        __syncthreads();
        cur ^= 1;
    }
    #undef STAGE_G

    // ---- epilogue via LDS pool (reuses As/Bs; last barrier above protects it) ----
    const int s = n0 / DIM_;                 // block-uniform (768 % 128 == 0)
    const int bq = m0 >> 11, nq0 = m0 & 2047;
    if (s == 2) {
        // pool_v[col(128)][row(128)], row-granule XOR swizzle
        #pragma unroll
        for (int j = 0; j < 4; ++j) {
            const int col = wc * 64 + j * 16 + q15;
            const int cs = (col & 7) << 3;
            #pragma unroll
            for (int i = 0; i < 4; ++i) {
                const int row0 = wr * 64 + i * 16 + g * 4;   // row0 % 8 in {0,4}
                ushort4 v;
                v.x = f2bf(acc[i][j][0]); v.y = f2bf(acc[i][j][1]);
                v.z = f2bf(acc[i][j][2]); v.w = f2bf(acc[i][j][3]);
                *(ushort4*)&pool[col * 128 + ((row0 & ~7) ^ cs) + (row0 & 7)] = v;
            }
        }
        __syncthreads();
        const int hh0 = (n0 - 2 * DIM_) >> 6;
        #pragma unroll
        for (int pass = 0; pass < 8; ++pass) {
            const int idx = pass * 256 + tid;        // 0..2047 16B-chunks
            const int t = idx >> 10;                  // head 0/1
            const int ddl = (idx & 1023) >> 4;        // d row 0..63
            const int tok0 = (idx & 15) << 3;         // 0..120
            const int col = t * 64 + ddl;
            const unsigned short* src = &pool[col * 128 + (tok0 ^ ((col & 7) << 3))];
            unsigned short* dst = vth + ((size_t)((bq * NH + hh0 + t) * 64 + ddl)) * NN + nq0 + tok0;
            *(ulonglong2*)dst = *(const ulonglong2*)src;
        }
    } else {
        // pool[row(128)][col(128)], col-granule XOR swizzle
        const float sc = (s == 0) ? QSCALE : 1.0f;
        #pragma unroll
        for (int j = 0; j < 4; ++j) {
            const int colE = wc * 64 + j * 16 + q15;
            #pragma unroll
            for (int i = 0; i < 4; ++i) {
                #pragma unroll
                for (int r = 0; r < 4; ++r) {
                    const int row = wr * 64 + i * 16 + g * 4 + r;
                    pool[row * 128 + (((colE & ~7) ^ ((row & 7) << 3)) | (colE & 7))] =
                        f2bf(acc[i][j][r] * sc);
                }
            }
        }
        __syncthreads();
        const int hh0 = (n0 - s * DIM_) >> 6;
        unsigned short* const dstb = (s == 0) ? qh : kh;
        #pragma unroll
        for (int pass = 0; pass < 8; ++pass) {
            const int idx = pass * 256 + tid;
            const int t = idx >> 10;
            const int off = idx & 1023;
            const int tok = off >> 3;
            const int d0 = (off & 7) << 3;            // 8-aligned
            const int colb = t * 64 + d0;
            const unsigned short* src = &pool[tok * 128 + (colb ^ ((tok & 7) << 3))];
            unsigned short* dst = dstb + ((size_t)((bq * NH + hh0 + t)) * NN + nq0 + tok) * 64 + d0;
            *(ulonglong2*)dst = *(const ulonglong2*)src;
        }
    }
}

// ---------------- GEMM2: out = xatt @ w_fc^T + b (128x64 tile, 384 blocks) ------
__global__ __launch_bounds__(256)
void gemm_fc(const unsigned short* __restrict__ A, const unsigned short* __restrict__ W,
             const float* __restrict__ bias, float* __restrict__ C, int Md, int Nd, int K)
{
    __shared__ unsigned short As[2][128 * 32];
    __shared__ unsigned short Bs[2][64 * 32];
    const int tid = threadIdx.x, lane = tid & 63, wave = tid >> 6;
    const int wr = wave >> 1, wc = wave & 1;
    const int n0 = blockIdx.x * 64, m0 = blockIdx.y * 128;
    const int ldrow = lane >> 2, ldg = lane & 3;

    f32x4 acc[4][2];
    #pragma unroll
    for (int i = 0; i < 4; ++i)
        #pragma unroll
        for (int j = 0; j < 2; ++j) acc[i][j] = (f32x4){0.f, 0.f, 0.f, 0.f};

    #define STAGE_G(buf, k0)                                                         \
        _Pragma("unroll")                                                            \
        for (int rd = 0; rd < 2; ++rd) {                                             \
            const int chunk = rd * 4 + wave;                                         \
            const int row = chunk * 16 + ldrow;                                      \
            gload16(A + (size_t)(m0 + row) * K + (k0) + ldg * 8,                     \
                    (char*)As[buf] + chunk * 1024);                                  \
        }                                                                            \
        gload16(W + (size_t)(n0 + wave * 16 + ldrow) * K + (k0) + ldg * 8,           \
                (char*)Bs[buf] + wave * 1024);

    STAGE_G(0, 0);
    __syncthreads();
    int cur = 0;
    const int nk = K / 32;
    for (int kt = 0; kt < nk; ++kt) {
        if (kt < nk - 1) { STAGE_G(cur ^ 1, (kt + 1) * 32); }
        bf16x8 af[4], bw[2];
        #pragma unroll
        for (int i = 0; i < 4; ++i)
            af[i] = *(const bf16x8*)((const char*)As[cur] + (wr*64 + i*16 + (lane & 15)) * 64 + (lane >> 4) * 16);
        #pragma unroll
        for (int j = 0; j < 2; ++j)
            bw[j] = *(const bf16x8*)((const char*)Bs[cur] + (wc*32 + j*16 + (lane & 15)) * 64 + (lane >> 4) * 16);
        #pragma unroll
        for (int i = 0; i < 4; ++i)
            #pragma unroll
            for (int j = 0; j < 2; ++j)
                acc[i][j] = __builtin_amdgcn_mfma_f32_16x16x32_bf16(af[i], bw[j], acc[i][j], 0, 0, 0);
        __syncthreads();
        cur ^= 1;
    }

    const int r0 = (lane >> 4) * 4, cl = lane & 15;
    #pragma unroll
    for (int i = 0; i < 4; ++i)
        #pragma unroll
        for (int j = 0; j < 2; ++j) {
            const int n = n0 + wc * 32 + j * 16 + cl;
            const float bv = bias[n];
            #pragma unroll
            for (int r = 0; r < 4; ++r) {
                const int m = m0 + wr * 64 + i * 16 + r0 + r;
                C[(size_t)m * Nd + n] = acc[i][j][r] + bv;
            }
        }
    #undef STAGE_G
}

// ---- Flash attention: swapped QK^T, in-register P transpose, defer-max ----------
__global__ __launch_bounds__(256)
void attn_mfma(const unsigned short* __restrict__ qh, const unsigned short* __restrict__ kh,
               const unsigned short* __restrict__ vth, const int* __restrict__ pmask,
               unsigned short* __restrict__ xout)
{
    __shared__ unsigned short Ks[2][64 * 64];     // 16KB
    __shared__ unsigned short Vs[2][64 * 64];     // 16KB (V^T tiles: [d][kv])
    __shared__ __align__(16) float maskLg[NN];    // 8KB: all masks for this b

    const int tid = threadIdx.x, lane = tid & 63, wave = tid >> 6;
    const int g = lane >> 4, q15 = lane & 15, l7 = lane & 7;
    const int X = (lane >> 5) & 1, Y = (lane >> 4) & 1;   // lane bits 5,4
    // XCD-aware swizzle: 768 blocks -> 96-block contiguous chunks per XCD
    const int swz = (blockIdx.x & 7) * 96 + (blockIdx.x >> 3);
    const int qt = swz & 31;
    const int bh = swz >> 5;
    const int h = bh % NH, b = bh / NH;
    const size_t base = (size_t)(b * NH + h) * NN * 64;

    const int sr = lane >> 3, sg = lane & 7;

    #define STAGE_KV(buf, kt)                                                          \
        _Pragma("unroll")                                                              \
        for (int rd = 0; rd < 2; ++rd) {                                               \
            const int chunk = rd * 4 + wave;                                           \
            const int row = chunk * 8 + sr;                                            \
            const int gs = (sg ^ (sr & 7)) * 8;                                        \
            gload16(kh + base + (size_t)((kt) * 64 + row) * 64 + gs,                   \
                    (char*)Ks[buf] + chunk * 1024);                                    \
            gload16(vth + base + (size_t)row * NN + (kt) * 64 + gs,                    \
                    (char*)Vs[buf] + chunk * 1024);                                    \
        }

    // prologue: stage tile0; preload all masks; Q fragments direct from global
    STAGE_KV(0, 0);
    #pragma unroll
    for (int jj = 0; jj < 2; ++jj) {
        const int j = jj * 256 + tid;                 // 512 int4 groups
        int4 mv = ((const int4*)(pmask + b * NN))[j];
        float4 mf;
        mf.x = mv.x > 0 ? -__builtin_inff() : 0.f;
        mf.y = mv.y > 0 ? -__builtin_inff() : 0.f;
        mf.z = mv.z > 0 ? -__builtin_inff() : 0.f;
        mf.w = mv.w > 0 ? -__builtin_inff() : 0.f;
        ((float4*)maskLg)[j] = mf;
    }
    bf16x8 qf[2];
    {
        const unsigned short* qp = qh + base + (size_t)(qt * 64 + wave * 16 + q15) * 64;
        qf[0] = *(const bf16x8*)(qp + g * 8);
        qf[1] = *(const bf16x8*)(qp + 32 + g * 8);
    }
    __syncthreads();

    float m = -1e30f, lsum = 0.f;
    f32x4 oacc[4];
    #pragma unroll
    for (int fo = 0; fo < 4; ++fo) oacc[fo] = (f32x4){0.f, 0.f, 0.f, 0.f};

    int cur = 0;
    for (int kt = 0; kt < NN / 64; ++kt) {
        if (kt < NN / 64 - 1) { STAGE_KV(cur ^ 1, kt + 1); }

        // ---- S^T = K Q^T + mask (acc: row=kv=f*16+g*4+r, col=q=lane&15) ----
        f32x4 s[4];
        #pragma unroll
        for (int f = 0; f < 4; ++f) s[f] = *(const f32x4*)&maskLg[kt * 64 + f * 16 + g * 4];
        __builtin_amdgcn_s_setprio(1);
        #pragma unroll
        for (int ks = 0; ks < 2; ++ks) {
            #pragma unroll
            for (int f = 0; f < 4; ++f) {
                const int krow = f * 16 + q15;
                const int gk = (g + ks * 4) ^ l7;
                bf16x8 kf = *(const bf16x8*)((const char*)Ks[cur] + krow * 128 + gk * 16);
                s[f] = __builtin_amdgcn_mfma_f32_16x16x32_bf16(kf, qf[ks], s[f], 0, 0, 0);
            }
        }
        __builtin_amdgcn_s_setprio(0);

        // ---- lane-local online softmax (log2 domain), defer-max ----
        float pmax;
        {
            const float a0 = fmaxf(fmaxf(s[0][0], s[0][1]), fmaxf(s[0][2], s[0][3]));
            const float a1 = fmaxf(fmaxf(s[1][0], s[1][1]), fmaxf(s[1][2], s[1][3]));
            const float a2 = fmaxf(fmaxf(s[2][0], s[2][1]), fmaxf(s[2][2], s[2][3]));
            const float a3 = fmaxf(fmaxf(s[3][0], s[3][1]), fmaxf(s[3][2], s[3][3]));
            pmax = fmaxf(fmaxf(a0, a1), fmaxf(a2, a3));
        }
        pmax = fmaxf(pmax, __shfl_xor(pmax, 16));
        pmax = fmaxf(pmax, __shfl_xor(pmax, 32));
        if (__any(pmax > m + 10.0f)) {
            const float mnew = fmaxf(m, pmax);
            const float corr = __builtin_amdgcn_exp2f(m - mnew);
            m = mnew;
            lsum *= corr;
            float c[4];
            #pragma unroll
            for (int r = 0; r < 4; ++r) c[r] = __shfl(corr, g * 4 + r);
            #pragma unroll
            for (int fo = 0; fo < 4; ++fo)
                #pragma unroll
                for (int r = 0; r < 4; ++r) oacc[fo][r] *= c[r];
        }
        float pw[4][4], ps = 0.f;
        #pragma unroll
        for (int f = 0; f < 4; ++f) {
            float psf = 0.f;
            #pragma unroll
            for (int r = 0; r < 4; ++r) {
                const float p = __builtin_amdgcn_exp2f(s[f][r] - m);
                pw[f][r] = p; psf += p;
            }
            ps += psf;
        }
        ps += __shfl_xor(ps, 16);
        ps += __shfl_xor(ps, 32);
        lsum += ps;

        // ---- in-register P transpose: (bit5, bit4, reg c) -> (reg, bit5, bit4) ----
        // PV A-frag needs lane (g',q): kv = ks*32 + g'*8 + 2*j2 {,+1}, j2=0..3.
        __builtin_amdgcn_s_setprio(1);
        #pragma unroll
        for (int ks = 0; ks < 2; ++ks) {
            // pack: D[c][d2] = pk(p[2ks+c][2d2], p[2ks+c][2d2+1])
            unsigned int D00 = cvt_pk_bf16(pw[2*ks+0][0], pw[2*ks+0][1]);
            unsigned int D01 = cvt_pk_bf16(pw[2*ks+0][2], pw[2*ks+0][3]);
            unsigned int D10 = cvt_pk_bf16(pw[2*ks+1][0], pw[2*ks+1][1]);
            unsigned int D11 = cvt_pk_bf16(pw[2*ks+1][2], pw[2*ks+1][3]);
            // step 1: swap lane-bit5 <-> c
            unsigned int r0 = (unsigned int)__shfl_xor((int)(X ? D00 : D10), 32);
            unsigned int r1 = (unsigned int)__shfl_xor((int)(X ? D01 : D11), 32);
            unsigned int E00 = X ? r0 : D00, E01 = X ? r1 : D01;
            unsigned int E10 = X ? D10 : r0, E11 = X ? D11 : r1;
            // step 2: swap lane-bit4 <-> c
            unsigned int u0 = (unsigned int)__shfl_xor((int)(Y ? E00 : E10), 16);
            unsigned int u1 = (unsigned int)__shfl_xor((int)(Y ? E01 : E11), 16);
            unsigned int F0 = Y ? u0 : E00, F1 = Y ? u1 : E01;
            unsigned int F2 = Y ? E10 : u0, F3 = Y ? E11 : u1;
            unsigned int pfw[4] = {F0, F1, F2, F3};
            bf16x8 pf;
            __builtin_memcpy(&pf, pfw, 16);
            #pragma unroll
            for (int fo = 0; fo < 4; ++fo) {
                const int gv = (g + ks * 4) ^ l7;
                bf16x8 vf = *(const bf16x8*)((const char*)Vs[cur] + (fo * 16 + q15) * 128 + gv * 16);
                oacc[fo] = __builtin_amdgcn_mfma_f32_16x16x32_bf16(pf, vf, oacc[fo], 0, 0, 0);
            }
        }
        __builtin_amdgcn_s_setprio(0);

        __syncthreads();
        cur ^= 1;
    }

    // epilogue: redistribute lsum (row q' = g*4+r held by lane q')
    float linv[4];
    #pragma unroll
    for (int r = 0; r < 4; ++r) linv[r] = 1.0f / __shfl(lsum, g * 4 + r);
    #pragma unroll
    for (int r = 0; r < 4; ++r) {
        const int q = qt * 64 + wave * 16 + g * 4 + r;
        #pragma unroll
        for (int fo = 0; fo < 4; ++fo) {
            const int d = fo * 16 + q15;
            xout[(size_t)(b * NN + q) * DIM_ + h * 64 + d] = f2bf(oacc[fo][r] * linv[r]);
        }
    }
    #undef STAGE_KV
}

extern "C" void kernel_launch(void* const* d_in, const int* in_sizes, int n_in,
                              void* d_out, int out_size, void* d_ws, size_t ws_size,
                              hipStream_t stream)
{
    const float* x     = (const float*)d_in[0];
    const int*   pmask = (const int*)d_in[1];
    const float* wqkv  = (const float*)d_in[2];
    const float* wfc   = (const float*)d_in[3];
    const float* bfc   = (const float*)d_in[4];
    float* out = (float*)d_out;

    const size_t n_x    = (size_t)MM * DIM_;
    const size_t n_wqkv = (size_t)QKVD * DIM_;
    const size_t n_wfc  = (size_t)DIM_ * DIM_;
    const size_t n_head = (size_t)BB * NH * NN * 64;

    unsigned short* xb    = (unsigned short*)d_ws;
    unsigned short* wqkvb = xb + n_x;
    unsigned short* wfcb  = wqkvb + n_wqkv;
    unsigned short* qhb   = wfcb + n_wfc;
    unsigned short* khb   = qhb + n_head;
    unsigned short* vthb  = khb + n_head;
    unsigned short* xattb = vthb + n_head;

    const int nv = (int)((n_x + n_wqkv + n_wfc) / 4);
    cast_all<<<(nv + 255) / 256, 256, 0, stream>>>(x, wqkv, wfc, xb, wqkvb, wfcb);

    gemm_qkv<<<dim3(QKVD / 128, MM / 128), 256, 0, stream>>>(xb, wqkvb, qhb, khb, vthb);
    attn_mfma<<<dim3(BB * NH * (NN / 64)), 256, 0, stream>>>(qhb, khb, vthb, pmask, xattb);
    gemm_fc<<<dim3(DIM_ / 64, MM / 128), 256, 0, stream>>>(xattb, wfcb, bfc, out, MM, DIM_, DIM_);
}

// Round 8
// 154.978 us; speedup vs baseline: 1.1899x; 1.1899x over previous
//
#include <hip/hip_runtime.h>
#include <hip/hip_bf16.h>

#define DIM_  768
#define NH    12
#define HD    64
#define BB    2
#define NN    2048
#define MM    (BB*NN)      // 4096
#define QKVD  (3*DIM_)     // 2304

typedef __attribute__((ext_vector_type(8))) short          bf16x8;
typedef __attribute__((ext_vector_type(4))) float          f32x4;

__device__ __forceinline__ unsigned short f2bf(float f) {
    __hip_bfloat16 h = __float2bfloat16(f);
    unsigned short u; __builtin_memcpy(&u, &h, 2); return u;
}

__device__ __forceinline__ unsigned int cvt_pk_bf16(float lo, float hi) {
    unsigned int r;
    asm("v_cvt_pk_bf16_f32 %0, %1, %2" : "=v"(r) : "v"(lo), "v"(hi));
    return r;
}

// async global->LDS, 16B/lane. LDS dest = wave-uniform base + lane*16 (HW rule);
// global SOURCE may be per-lane.
__device__ __forceinline__ void gload16(const void* g, void* lds) {
    __builtin_amdgcn_global_load_lds(
        (const __attribute__((address_space(1))) void*)g,
        (__attribute__((address_space(3))) void*)lds, 16, 0, 0);
}

// one fused cast kernel: x, w_qkv, w_fc -> bf16
__global__ __launch_bounds__(256)
void cast_all(const float* __restrict__ x, const float* __restrict__ wqkv,
              const float* __restrict__ wfc, unsigned short* __restrict__ xb,
              unsigned short* __restrict__ wqkvb, unsigned short* __restrict__ wfcb)
{
    const int NV0 = (MM * DIM_) / 4;
    const int NV1 = NV0 + (QKVD * DIM_) / 4;
    const int NV2 = NV1 + (DIM_ * DIM_) / 4;
    int i = blockIdx.x * 256 + threadIdx.x;
    if (i >= NV2) return;
    const float* src; unsigned short* dst;
    if (i < NV0)      { src = x + (size_t)i * 4;            dst = xb + (size_t)i * 4; }
    else if (i < NV1) { size_t j = i - NV0; src = wqkv + j * 4; dst = wqkvb + j * 4; }
    else              { size_t j = i - NV1; src = wfc + j * 4;  dst = wfcb + j * 4; }
    float4 v = *(const float4*)src;
    ushort4 o; o.x = f2bf(v.x); o.y = f2bf(v.y); o.z = f2bf(v.z); o.w = f2bf(v.w);
    *(ushort4*)dst = o;
}

// ---- per-batch stable compaction of unmasked key indices -----------------------
__global__ __launch_bounds__(256)
void scan_mask(const int* __restrict__ pmask, int* __restrict__ kidx, int* __restrict__ count)
{
    __shared__ int sums[256];
    __shared__ int base[256];
    const int b = blockIdx.x, tid = threadIdx.x;
    const int* pm = pmask + b * NN;
    int* ki = kidx + b * NN;
    #pragma unroll
    for (int j = 0; j < 8; ++j) ki[tid * 8 + j] = 0;   // pad entries -> token 0
    int mloc[8], s8 = 0;
    #pragma unroll
    for (int j = 0; j < 8; ++j) { mloc[j] = pm[tid * 8 + j]; s8 += (mloc[j] == 0); }
    sums[tid] = s8;
    __syncthreads();
    if (tid == 0) {
        int acc = 0;
        for (int i = 0; i < 256; ++i) { base[i] = acc; acc += sums[i]; }
        count[b] = acc;
    }
    __syncthreads();
    int pos = base[tid];
    #pragma unroll
    for (int j = 0; j < 8; ++j)
        if (mloc[j] == 0) ki[pos++] = tid * 8 + j;
}

// ---------------- GEMM1: qkv = x @ w_qkv^T -> q (all tokens, pre-scaled),
//                  k/v^T COMPACTED to unmasked tokens via kidx gather ------------
__global__ __launch_bounds__(256)
void gemm_qkv(const unsigned short* __restrict__ A, const unsigned short* __restrict__ W,
              const int* __restrict__ kidx, const int* __restrict__ count,
              unsigned short* __restrict__ qh, unsigned short* __restrict__ kh,
              unsigned short* __restrict__ vth)
{
    __shared__ unsigned short smem[4][4096];   // As = smem[0..1], Bs = smem[2..3]; pool = all
    unsigned short* const pool = &smem[0][0];
    const int tid = threadIdx.x, lane = tid & 63, wave = tid >> 6;
    const int wr = wave >> 1, wc = wave & 1;
    const int n0 = blockIdx.x * 128, m0 = blockIdx.y * 128;
    const int ldrow = lane >> 2, ldg = lane & 3;
    const int g = lane >> 4, q15 = lane & 15;
    constexpr float QSCALE = 0.18033688011112042f;   // 64^-0.5 * log2(e)

    const int s = n0 / DIM_;                  // block-uniform (768 % 128 == 0)
    const int bq = m0 >> 11, p0 = m0 & 2047;
    if (s >= 1) {
        const int padc = (count[bq] + 127) & ~127;
        if (p0 >= padc) return;               // compact range exhausted
    }

    // per-thread A-row offsets (gathered through kidx for k/v parts)
    size_t arow[2];
    #pragma unroll
    for (int rd = 0; rd < 2; ++rd) {
        const int row = (rd * 4 + wave) * 16 + ldrow;
        int tok;
        if (s == 0) tok = m0 + row;
        else        tok = bq * NN + kidx[bq * NN + p0 + row];
        arow[rd] = (size_t)tok * DIM_ + ldg * 8;
    }

    f32x4 acc[4][4];
    #pragma unroll
    for (int i = 0; i < 4; ++i)
        #pragma unroll
        for (int j = 0; j < 4; ++j) acc[i][j] = (f32x4){0.f, 0.f, 0.f, 0.f};

    #define STAGE_G(buf, k0)                                                         \
        _Pragma("unroll")                                                            \
        for (int rd = 0; rd < 2; ++rd) {                                             \
            const int chunk = rd * 4 + wave;                                         \
            gload16(A + arow[rd] + (k0), (char*)&smem[buf][0] + chunk * 1024);       \
            gload16(W + (size_t)(n0 + chunk * 16 + ldrow) * DIM_ + (k0) + ldg * 8,   \
                    (char*)&smem[2 + (buf)][0] + chunk * 1024);                      \
        }

    STAGE_G(0, 0);
    __syncthreads();
    int cur = 0;
    for (int kt = 0; kt < DIM_ / 32; ++kt) {
        if (kt < DIM_ / 32 - 1) { STAGE_G(cur ^ 1, (kt + 1) * 32); }
        bf16x8 af[4], bw[4];
        #pragma unroll
        for (int i = 0; i < 4; ++i)
            af[i] = *(const bf16x8*)((const char*)&smem[cur][0] + (wr*64 + i*16 + q15) * 64 + g * 16);
        #pragma unroll
        for (int j = 0; j < 4; ++j)
            bw[j] = *(const bf16x8*)((const char*)&smem[2 + cur][0] + (wc*64 + j*16 + q15) * 64 + g * 16);
        #pragma unroll
        for (int i = 0; i < 4; ++i)
            #pragma unroll
            for (int j = 0; j < 4; ++j)
                acc[i][j] = __builtin_amdgcn_mfma_f32_16x16x32_bf16(af[i], bw[j], acc[i][j], 0, 0, 0);
        __syncthreads();
        cur ^= 1;
    }
    #undef STAGE_G

    // ---- epilogue via LDS pool (rows of the M-range = token/compact positions) --
    if (s == 2) {
        // pool_v[col(128)][row(128)], row-granule XOR swizzle
        #pragma unroll
        for (int j = 0; j < 4; ++j) {
            const int col = wc * 64 + j * 16 + q15;
            const int cs = (col & 7) << 3;
            #pragma unroll
            for (int i = 0; i < 4; ++i) {
                const int row0 = wr * 64 + i * 16 + g * 4;
                ushort4 v;
                v.x = f2bf(acc[i][j][0]); v.y = f2bf(acc[i][j][1]);
                v.z = f2bf(acc[i][j][2]); v.w = f2bf(acc[i][j][3]);
                *(ushort4*)&pool[col * 128 + ((row0 & ~7) ^ cs) + (row0 & 7)] = v;
            }
        }
        __syncthreads();
        const int hh0 = (n0 - 2 * DIM_) >> 6;
        #pragma unroll
        for (int pass = 0; pass < 8; ++pass) {
            const int idx = pass * 256 + tid;
            const int t = idx >> 10;
            const int ddl = (idx & 1023) >> 4;
            const int tok0 = (idx & 15) << 3;
            const int col = t * 64 + ddl;
            const unsigned short* src = &pool[col * 128 + (tok0 ^ ((col & 7) << 3))];
            unsigned short* dst = vth + ((size_t)((bq * NH + hh0 + t) * 64 + ddl)) * NN + p0 + tok0;
            *(ulonglong2*)dst = *(const ulonglong2*)src;
        }
    } else {
        // pool[row(128)][col(128)], col-granule XOR swizzle
        const float sc = (s == 0) ? QSCALE : 1.0f;
        #pragma unroll
        for (int j = 0; j < 4; ++j) {
            const int colE = wc * 64 + j * 16 + q15;
            #pragma unroll
            for (int i = 0; i < 4; ++i) {
                #pragma unroll
                for (int r = 0; r < 4; ++r) {
                    const int row = wr * 64 + i * 16 + g * 4 + r;
                    pool[row * 128 + (((colE & ~7) ^ ((row & 7) << 3)) | (colE & 7))] =
                        f2bf(acc[i][j][r] * sc);
                }
            }
        }
        __syncthreads();
        const int hh0 = (n0 - s * DIM_) >> 6;
        unsigned short* const dstb = (s == 0) ? qh : kh;
        #pragma unroll
        for (int pass = 0; pass < 8; ++pass) {
            const int idx = pass * 256 + tid;
            const int t = idx >> 10;
            const int off = idx & 1023;
            const int tok = off >> 3;
            const int d0 = (off & 7) << 3;
            const int colb = t * 64 + d0;
            const unsigned short* src = &pool[tok * 128 + (colb ^ ((tok & 7) << 3))];
            unsigned short* dst = dstb + ((size_t)((bq * NH + hh0 + t)) * NN + p0 + tok) * 64 + d0;
            *(ulonglong2*)dst = *(const ulonglong2*)src;
        }
    }
}

// ---------------- GEMM2: out = xatt @ w_fc^T + b (128x64 tile, 384 blocks) ------
__global__ __launch_bounds__(256)
void gemm_fc(const unsigned short* __restrict__ A, const unsigned short* __restrict__ W,
             const float* __restrict__ bias, float* __restrict__ C, int Md, int Nd, int K)
{
    __shared__ unsigned short As[2][128 * 32];
    __shared__ unsigned short Bs[2][64 * 32];
    const int tid = threadIdx.x, lane = tid & 63, wave = tid >> 6;
    const int wr = wave >> 1, wc = wave & 1;
    const int n0 = blockIdx.x * 64, m0 = blockIdx.y * 128;
    const int ldrow = lane >> 2, ldg = lane & 3;

    f32x4 acc[4][2];
    #pragma unroll
    for (int i = 0; i < 4; ++i)
        #pragma unroll
        for (int j = 0; j < 2; ++j) acc[i][j] = (f32x4){0.f, 0.f, 0.f, 0.f};

    #define STAGE_G(buf, k0)                                                         \
        _Pragma("unroll")                                                            \
        for (int rd = 0; rd < 2; ++rd) {                                             \
            const int chunk = rd * 4 + wave;                                         \
            const int row = chunk * 16 + ldrow;                                      \
            gload16(A + (size_t)(m0 + row) * K + (k0) + ldg * 8,                     \
                    (char*)As[buf] + chunk * 1024);                                  \
        }                                                                            \
        gload16(W + (size_t)(n0 + wave * 16 + ldrow) * K + (k0) + ldg * 8,           \
                (char*)Bs[buf] + wave * 1024);

    STAGE_G(0, 0);
    __syncthreads();
    int cur = 0;
    const int nk = K / 32;
    for (int kt = 0; kt < nk; ++kt) {
        if (kt < nk - 1) { STAGE_G(cur ^ 1, (kt + 1) * 32); }
        bf16x8 af[4], bw[2];
        #pragma unroll
        for (int i = 0; i < 4; ++i)
            af[i] = *(const bf16x8*)((const char*)As[cur] + (wr*64 + i*16 + (lane & 15)) * 64 + (lane >> 4) * 16);
        #pragma unroll
        for (int j = 0; j < 2; ++j)
            bw[j] = *(const bf16x8*)((const char*)Bs[cur] + (wc*32 + j*16 + (lane & 15)) * 64 + (lane >> 4) * 16);
        #pragma unroll
        for (int i = 0; i < 4; ++i)
            #pragma unroll
            for (int j = 0; j < 2; ++j)
                acc[i][j] = __builtin_amdgcn_mfma_f32_16x16x32_bf16(af[i], bw[j], acc[i][j], 0, 0, 0);
        __syncthreads();
        cur ^= 1;
    }

    const int r0 = (lane >> 4) * 4, cl = lane & 15;
    #pragma unroll
    for (int i = 0; i < 4; ++i)
        #pragma unroll
        for (int j = 0; j < 2; ++j) {
            const int n = n0 + wc * 32 + j * 16 + cl;
            const float bv = bias[n];
            #pragma unroll
            for (int r = 0; r < 4; ++r) {
                const int m = m0 + wr * 64 + i * 16 + r0 + r;
                C[(size_t)m * Nd + n] = acc[i][j][r] + bv;
            }
        }
    #undef STAGE_G
}

// ---- Flash attention over COMPACT keys: swapped QK^T, in-reg P transpose --------
__global__ __launch_bounds__(256)
void attn_mfma(const unsigned short* __restrict__ qh, const unsigned short* __restrict__ kh,
               const unsigned short* __restrict__ vth, const int* __restrict__ count,
               unsigned short* __restrict__ xout)
{
    __shared__ unsigned short Ks[2][64 * 64];     // 16KB
    __shared__ unsigned short Vs[2][64 * 64];     // 16KB (V^T tiles: [d][kv])

    const int tid = threadIdx.x, lane = tid & 63, wave = tid >> 6;
    const int g = lane >> 4, q15 = lane & 15, l7 = lane & 7;
    const int X = (lane >> 5) & 1, Y = (lane >> 4) & 1;
    const int swz = (blockIdx.x & 7) * 96 + (blockIdx.x >> 3);
    const int qt = swz & 31;
    const int bh = swz >> 5;
    const int h = bh % NH, b = bh / NH;
    const size_t base = (size_t)(b * NH + h) * NN * 64;

    const int sr = lane >> 3, sg = lane & 7;
    const int cnt = count[b];
    const int nt = (cnt + 63) >> 6;

    #define STAGE_KV(buf, kt)                                                          \
        _Pragma("unroll")                                                              \
        for (int rd = 0; rd < 2; ++rd) {                                               \
            const int chunk = rd * 4 + wave;                                           \
            const int row = chunk * 8 + sr;                                            \
            const int gs = (sg ^ (sr & 7)) * 8;                                        \
            gload16(kh + base + (size_t)((kt) * 64 + row) * 64 + gs,                   \
                    (char*)Ks[buf] + chunk * 1024);                                    \
            gload16(vth + base + (size_t)row * NN + (kt) * 64 + gs,                    \
                    (char*)Vs[buf] + chunk * 1024);                                    \
        }

    // prologue: stage tile0; Q fragments direct from global
    STAGE_KV(0, 0);
    bf16x8 qf[2];
    {
        const unsigned short* qp = qh + base + (size_t)(qt * 64 + wave * 16 + q15) * 64;
        qf[0] = *(const bf16x8*)(qp + g * 8);
        qf[1] = *(const bf16x8*)(qp + 32 + g * 8);
    }
    __syncthreads();

    float m = -1e30f, lsum = 0.f;
    f32x4 oacc[4];
    #pragma unroll
    for (int fo = 0; fo < 4; ++fo) oacc[fo] = (f32x4){0.f, 0.f, 0.f, 0.f};

    int cur = 0;
    for (int kt = 0; kt < nt; ++kt) {
        if (kt + 1 < nt) { STAGE_KV(cur ^ 1, kt + 1); }

        // ---- S^T = K Q^T (+ tail -inf) (acc: row=kv=f*16+g*4+r, col=q=lane&15) --
        f32x4 s[4];
        if ((kt + 1) * 64 <= cnt) {
            #pragma unroll
            for (int f = 0; f < 4; ++f) s[f] = (f32x4){0.f, 0.f, 0.f, 0.f};
        } else {
            const int kb = kt * 64 + g * 4;
            #pragma unroll
            for (int f = 0; f < 4; ++f)
                #pragma unroll
                for (int r = 0; r < 4; ++r)
                    s[f][r] = (kb + f * 16 + r < cnt) ? 0.f : -__builtin_inff();
        }
        __builtin_amdgcn_s_setprio(1);
        #pragma unroll
        for (int ks = 0; ks < 2; ++ks) {
            #pragma unroll
            for (int f = 0; f < 4; ++f) {
                const int krow = f * 16 + q15;
                const int gk = (g + ks * 4) ^ l7;
                bf16x8 kf = *(const bf16x8*)((const char*)Ks[cur] + krow * 128 + gk * 16);
                s[f] = __builtin_amdgcn_mfma_f32_16x16x32_bf16(kf, qf[ks], s[f], 0, 0, 0);
            }
        }
        __builtin_amdgcn_s_setprio(0);

        // ---- lane-local online softmax (log2 domain), defer-max ----
        float pmax;
        {
            const float a0 = fmaxf(fmaxf(s[0][0], s[0][1]), fmaxf(s[0][2], s[0][3]));
            const float a1 = fmaxf(fmaxf(s[1][0], s[1][1]), fmaxf(s[1][2], s[1][3]));
            const float a2 = fmaxf(fmaxf(s[2][0], s[2][1]), fmaxf(s[2][2], s[2][3]));
            const float a3 = fmaxf(fmaxf(s[3][0], s[3][1]), fmaxf(s[3][2], s[3][3]));
            pmax = fmaxf(fmaxf(a0, a1), fmaxf(a2, a3));
        }
        pmax = fmaxf(pmax, __shfl_xor(pmax, 16));
        pmax = fmaxf(pmax, __shfl_xor(pmax, 32));
        if (__any(pmax > m + 10.0f)) {
            const float mnew = fmaxf(m, pmax);
            const float corr = __builtin_amdgcn_exp2f(m - mnew);
            m = mnew;
            lsum *= corr;
            float c[4];
            #pragma unroll
            for (int r = 0; r < 4; ++r) c[r] = __shfl(corr, g * 4 + r);
            #pragma unroll
            for (int fo = 0; fo < 4; ++fo)
                #pragma unroll
                for (int r = 0; r < 4; ++r) oacc[fo][r] *= c[r];
        }
        float pw[4][4], ps = 0.f;
        #pragma unroll
        for (int f = 0; f < 4; ++f) {
            float psf = 0.f;
            #pragma unroll
            for (int r = 0; r < 4; ++r) {
                const float p = __builtin_amdgcn_exp2f(s[f][r] - m);
                pw[f][r] = p; psf += p;
            }
            ps += psf;
        }
        ps += __shfl_xor(ps, 16);
        ps += __shfl_xor(ps, 32);
        lsum += ps;

        // ---- in-register P transpose: (bit5, bit4, reg c) -> (reg, bit5, bit4) --
        __builtin_amdgcn_s_setprio(1);
        #pragma unroll
        for (int ks = 0; ks < 2; ++ks) {
            unsigned int D00 = cvt_pk_bf16(pw[2*ks+0][0], pw[2*ks+0][1]);
            unsigned int D01 = cvt_pk_bf16(pw[2*ks+0][2], pw[2*ks+0][3]);
            unsigned int D10 = cvt_pk_bf16(pw[2*ks+1][0], pw[2*ks+1][1]);
            unsigned int D11 = cvt_pk_bf16(pw[2*ks+1][2], pw[2*ks+1][3]);
            unsigned int r0 = (unsigned int)__shfl_xor((int)(X ? D00 : D10), 32);
            unsigned int r1 = (unsigned int)__shfl_xor((int)(X ? D01 : D11), 32);
            unsigned int E00 = X ? r0 : D00, E01 = X ? r1 : D01;
            unsigned int E10 = X ? D10 : r0, E11 = X ? D11 : r1;
            unsigned int u0 = (unsigned int)__shfl_xor((int)(Y ? E00 : E10), 16);
            unsigned int u1 = (unsigned int)__shfl_xor((int)(Y ? E01 : E11), 16);
            unsigned int F0 = Y ? u0 : E00, F1 = Y ? u1 : E01;
            unsigned int F2 = Y ? E10 : u0, F3 = Y ? E11 : u1;
            unsigned int pfw[4] = {F0, F1, F2, F3};
            bf16x8 pf;
            __builtin_memcpy(&pf, pfw, 16);
            #pragma unroll
            for (int fo = 0; fo < 4; ++fo) {
                const int gv = (g + ks * 4) ^ l7;
                bf16x8 vf = *(const bf16x8*)((const char*)Vs[cur] + (fo * 16 + q15) * 128 + gv * 16);
                oacc[fo] = __builtin_amdgcn_mfma_f32_16x16x32_bf16(pf, vf, oacc[fo], 0, 0, 0);
            }
        }
        __builtin_amdgcn_s_setprio(0);

        __syncthreads();
        cur ^= 1;
    }

    // epilogue: redistribute lsum (row q' = g*4+r held by lane q')
    float linv[4];
    #pragma unroll
    for (int r = 0; r < 4; ++r) linv[r] = 1.0f / __shfl(lsum, g * 4 + r);
    #pragma unroll
    for (int r = 0; r < 4; ++r) {
        const int q = qt * 64 + wave * 16 + g * 4 + r;
        #pragma unroll
        for (int fo = 0; fo < 4; ++fo) {
            const int d = fo * 16 + q15;
            xout[(size_t)(b * NN + q) * DIM_ + h * 64 + d] = f2bf(oacc[fo][r] * linv[r]);
        }
    }
    #undef STAGE_KV
}

extern "C" void kernel_launch(void* const* d_in, const int* in_sizes, int n_in,
                              void* d_out, int out_size, void* d_ws, size_t ws_size,
                              hipStream_t stream)
{
    const float* x     = (const float*)d_in[0];
    const int*   pmask = (const int*)d_in[1];
    const float* wqkv  = (const float*)d_in[2];
    const float* wfc   = (const float*)d_in[3];
    const float* bfc   = (const float*)d_in[4];
    float* out = (float*)d_out;

    const size_t n_x    = (size_t)MM * DIM_;
    const size_t n_wqkv = (size_t)QKVD * DIM_;
    const size_t n_wfc  = (size_t)DIM_ * DIM_;
    const size_t n_head = (size_t)BB * NH * NN * 64;

    unsigned short* xb    = (unsigned short*)d_ws;
    unsigned short* wqkvb = xb + n_x;
    unsigned short* wfcb  = wqkvb + n_wqkv;
    unsigned short* qhb   = wfcb + n_wfc;
    unsigned short* khb   = qhb + n_head;
    unsigned short* vthb  = khb + n_head;
    unsigned short* xattb = vthb + n_head;
    int* kidx = (int*)(xattb + n_x);
    int* cnt  = kidx + BB * NN;

    const int nv = (int)((n_x + n_wqkv + n_wfc) / 4);
    cast_all<<<(nv + 255) / 256, 256, 0, stream>>>(x, wqkv, wfc, xb, wqkvb, wfcb);
    scan_mask<<<BB, 256, 0, stream>>>(pmask, kidx, cnt);

    gemm_qkv<<<dim3(QKVD / 128, MM / 128), 256, 0, stream>>>(xb, wqkvb, kidx, cnt, qhb, khb, vthb);
    attn_mfma<<<dim3(BB * NH * (NN / 64)), 256, 0, stream>>>(qhb, khb, vthb, cnt, xattb);
    gemm_fc<<<dim3(DIM_ / 64, MM / 128), 256, 0, stream>>>(xattb, wfcb, bfc, out, MM, DIM_, DIM_);
}